// Round 12
// baseline (309.898 us; speedup 1.0000x reference)
//
#include <hip/hip_runtime.h>
#include <cstdint>
#include <cstddef>

#define M_DIM 8192
#define N_DIM 4096
#define K_DIM 4096

typedef _Float16 f16x8 __attribute__((ext_vector_type(8)));
typedef float f32x4 __attribute__((ext_vector_type(4)));
typedef unsigned short ushort8 __attribute__((ext_vector_type(8)));

#define GLOAD_LDS16(g, l)                                                      \
  __builtin_amdgcn_global_load_lds(                                            \
      (const __attribute__((address_space(1))) void*)(g),                      \
      (__attribute__((address_space(3))) void*)(l), 16, 0, 0)

// code c in {0,1,2} -> fp16 bits of (c-1)
__device__ inline uint32_t lutf16(uint32_t c) {
  return (c == 1u) ? 0u : (0x3C00u | ((uint32_t)(c == 0u) << 15));
}

// ---- prep: X f32 [M,K] -> f16 [M,K] in ws (exact: values fp16-origin) ----
__global__ __launch_bounds__(256) void prep_x(const float4* __restrict__ X,
                                              ushort8* __restrict__ Xf) {
  int i = blockIdx.x * 256 + threadIdx.x;
  float4 f0 = X[2 * (size_t)i], f1 = X[2 * (size_t)i + 1];
  ushort8 us;
  us[0] = __builtin_bit_cast(uint16_t, (_Float16)f0.x);
  us[1] = __builtin_bit_cast(uint16_t, (_Float16)f0.y);
  us[2] = __builtin_bit_cast(uint16_t, (_Float16)f0.z);
  us[3] = __builtin_bit_cast(uint16_t, (_Float16)f0.w);
  us[4] = __builtin_bit_cast(uint16_t, (_Float16)f1.x);
  us[5] = __builtin_bit_cast(uint16_t, (_Float16)f1.y);
  us[6] = __builtin_bit_cast(uint16_t, (_Float16)f1.z);
  us[7] = __builtin_bit_cast(uint16_t, (_Float16)f1.w);
  Xf[i] = us;
}

// ---- prep: W int32 [N,K/4] (1 byte/word) -> f16 [N,K] in ws ----
__global__ __launch_bounds__(256) void prep_w(const uint2* __restrict__ W,
                                              uint4* __restrict__ Wf) {
  int i = blockIdx.x * 256 + threadIdx.x;
  uint2 wv = W[(size_t)i];
  uint32_t x = wv.x & 0xFFu, y = wv.y & 0xFFu;
  uint4 o;
  o.x = lutf16(x & 3u) | (lutf16((x >> 2) & 3u) << 16);
  o.y = lutf16((x >> 4) & 3u) | (lutf16((x >> 6) & 3u) << 16);
  o.z = lutf16(y & 3u) | (lutf16((y >> 2) & 3u) << 16);
  o.w = lutf16((y >> 4) & 3u) | (lutf16((y >> 6) & 3u) << 16);
  Wf[i] = o;
}

// ---- 128x256 BK=32 GEMM, 4 waves, 2 blocks/CU (cross-block overlap) ----
// Per-wave 64x128 out (acc 4x8 f32x4 = 128 AGPR). Dbuf LDS 48KB. Simple
// 2-barrier loop + counted vmcnt(6). Swizzle: chunk' = kg ^ ((row>>1)&3)
// -> 2 lanes/bank-group on ds_read_b128 = conflict-free; staging keeps LDS
// dest linear (global_load_lds) and pre-swizzles the global source chunk.
__global__ __launch_bounds__(256, 2) void gemm32(
    const _Float16* __restrict__ A,  // [M,K] f16 (ws)
    const _Float16* __restrict__ B,  // [N,K] f16 (ws)
    const float* __restrict__ G,     // gamma f32
    float* __restrict__ C) {         // [M,N] f32
  __shared__ __align__(16) _Float16 As[2][128 * 32];
  __shared__ __align__(16) _Float16 Bs[2][256 * 32];

  const int tid = threadIdx.x;
  const int wave = tid >> 6, lane = tid & 63;
  const int wr = wave >> 1, wc = wave & 1;   // 2M x 2N
  const int fr = lane & 15, kg = lane >> 4;

  int bid = (int)blockIdx.x;                       // 1024 blocks
  int swz = (bid & 7) * 128 + (bid >> 3);          // XCD-contig, bijective
  const int bm = (swz >> 4) * 128;                 // 64 M-tiles
  const int bn = (swz & 15) * 256;                 // 16 N-tiles

  const int sr = lane >> 2;                        // row within 16-row seg
  const int scc = (lane & 3) ^ ((lane >> 3) & 3);  // pre-swizzled src chunk

  f32x4 acc[4][8] = {};

#define STG(t)                                                                 \
  do {                                                                         \
    const int b_ = (t) & 1;                                                    \
    const int kt_ = (t) * 32;                                                  \
    _Pragma("unroll") for (int j_ = 0; j_ < 6; ++j_) {                         \
      int sg_ = wave * 6 + j_;   /* 0..23: A segs 0-7, B segs 8-23 */          \
      if (sg_ < 8) {                                                           \
        GLOAD_LDS16(                                                           \
            A + (size_t)(bm + sg_ * 16 + sr) * K_DIM + kt_ + scc * 8,          \
            As[b_] + sg_ * 512);                                               \
      } else {                                                                 \
        int s2_ = sg_ - 8;                                                     \
        GLOAD_LDS16(                                                           \
            B + (size_t)(bn + s2_ * 16 + sr) * K_DIM + kt_ + scc * 8,          \
            Bs[b_] + s2_ * 512);                                               \
      }                                                                        \
    }                                                                          \
  } while (0)

#define BODY(t, LAST)                                                          \
  do {                                                                         \
    if (!(LAST)) STG((t) + 1);                                                 \
    if (LAST)                                                                  \
      asm volatile("s_waitcnt vmcnt(0)" ::: "memory");                         \
    else                                                                       \
      asm volatile("s_waitcnt vmcnt(6)" ::: "memory");                         \
    __builtin_amdgcn_s_barrier();                                              \
    const int b_ = (t) & 1;                                                    \
    f16x8 af[4], bf[8];                                                        \
    _Pragma("unroll") for (int m_ = 0; m_ < 4; ++m_) {                         \
      int row_ = wr * 64 + m_ * 16 + fr;                                       \
      af[m_] = *reinterpret_cast<const f16x8*>(                                \
          As[b_] + row_ * 32 + ((kg ^ ((row_ >> 1) & 3)) * 8));                \
    }                                                                          \
    _Pragma("unroll") for (int n_ = 0; n_ < 8; ++n_) {                         \
      int row_ = wc * 128 + n_ * 16 + fr;                                      \
      bf[n_] = *reinterpret_cast<const f16x8*>(                                \
          Bs[b_] + row_ * 32 + ((kg ^ ((row_ >> 1) & 3)) * 8));                \
    }                                                                          \
    __builtin_amdgcn_s_setprio(1);                                             \
    _Pragma("unroll") for (int m_ = 0; m_ < 4; ++m_)                           \
      _Pragma("unroll") for (int n_ = 0; n_ < 8; ++n_)                         \
        acc[m_][n_] = __builtin_amdgcn_mfma_f32_16x16x32_f16(                  \
            af[m_], bf[n_], acc[m_][n_], 0, 0, 0);                             \
    __builtin_amdgcn_s_setprio(0);                                             \
    __builtin_amdgcn_s_barrier();                                              \
  } while (0)

  STG(0);
  for (int t = 0; t < 126; t += 2) {
    BODY(t, false);
    BODY(t + 1, false);
  }
  BODY(126, false);
  BODY(127, true);
#undef STG
#undef BODY

  float g = G[0];
  if (!(__builtin_fabsf(g) >= 0.001f && __builtin_fabsf(g) <= 1000.0f)) g = 1.0f;
#pragma unroll
  for (int m = 0; m < 4; ++m)
#pragma unroll
    for (int n = 0; n < 8; ++n) {
      int col = bn + wc * 128 + n * 16 + fr;
      int row0 = bm + wr * 64 + m * 16 + kg * 4;
#pragma unroll
      for (int j = 0; j < 4; ++j)
        C[(size_t)(row0 + j) * N_DIM + col] = acc[m][n][j] * g;
    }
}

// ---- fallback GEMM (ws too small): inline cvt/decode, XOR-swizzled LDS ----
__global__ __launch_bounds__(256) void gemm_inline(
    const float* __restrict__ X, const uint32_t* __restrict__ W,
    const float* __restrict__ G, float* __restrict__ C) {
  __shared__ __align__(16) _Float16 As[128 * 64];
  __shared__ __align__(16) _Float16 Bs[128 * 64];

  const int tid = threadIdx.x;
  const int wave = tid >> 6;
  const int lane = tid & 63;
  const int wr = wave >> 1, wc = wave & 1;
  const int fr = lane & 15, kg = lane >> 4;
  const int bm = blockIdx.y * 128, bn = blockIdx.x * 128;
  const int brow = tid >> 1, bhalf = tid & 1;

  f32x4 acc[4][4] = {};

  for (int kt = 0; kt < K_DIM; kt += 64) {
#pragma unroll
    for (int i = 0; i < 4; ++i) {
      int c = i * 256 + tid;
      int row = c >> 3, cc = c & 7;
      const float4* p =
          (const float4*)(X + (size_t)(bm + row) * K_DIM + kt + cc * 8);
      float4 f0 = p[0], f1 = p[1];
      ushort8 us;
      us[0] = __builtin_bit_cast(uint16_t, (_Float16)f0.x);
      us[1] = __builtin_bit_cast(uint16_t, (_Float16)f0.y);
      us[2] = __builtin_bit_cast(uint16_t, (_Float16)f0.z);
      us[3] = __builtin_bit_cast(uint16_t, (_Float16)f0.w);
      us[4] = __builtin_bit_cast(uint16_t, (_Float16)f1.x);
      us[5] = __builtin_bit_cast(uint16_t, (_Float16)f1.y);
      us[6] = __builtin_bit_cast(uint16_t, (_Float16)f1.z);
      us[7] = __builtin_bit_cast(uint16_t, (_Float16)f1.w);
      *reinterpret_cast<ushort8*>((uint16_t*)As + row * 64 +
                                  (cc ^ (row & 7)) * 8) = us;
    }
    {
      const uint32_t* wp =
          W + (size_t)(bn + brow) * 1024 + (kt >> 2) + bhalf * 8;
      uint32_t w[8];
      *(uint4*)(w) = *(const uint4*)(wp);
      *(uint4*)(w + 4) = *(const uint4*)(wp + 4);
#pragma unroll
      for (int q = 0; q < 4; ++q) {
        uint32_t x = w[2 * q] & 0xFFu, y = w[2 * q + 1] & 0xFFu;
        uint4 o;
        o.x = lutf16(x & 3u) | (lutf16((x >> 2) & 3u) << 16);
        o.y = lutf16((x >> 4) & 3u) | (lutf16((x >> 6) & 3u) << 16);
        o.z = lutf16(y & 3u) | (lutf16((y >> 2) & 3u) << 16);
        o.w = lutf16((y >> 4) & 3u) | (lutf16((y >> 6) & 3u) << 16);
        int slot = (bhalf * 4 + q) ^ (brow & 7);
        *reinterpret_cast<uint4*>((uint16_t*)Bs + brow * 64 + slot * 8) = o;
      }
    }
    __syncthreads();

#pragma unroll
    for (int ks = 0; ks < 2; ++ks) {
      f16x8 a[4], b[4];
#pragma unroll
      for (int r = 0; r < 4; ++r) {
        int row = wr * 64 + r * 16 + fr;
        a[r] = *reinterpret_cast<const f16x8*>(
            As + row * 64 + ((ks * 4 + kg) ^ (row & 7)) * 8);
      }
#pragma unroll
      for (int c = 0; c < 4; ++c) {
        int row = wc * 64 + c * 16 + fr;
        b[c] = *reinterpret_cast<const f16x8*>(
            Bs + row * 64 + ((ks * 4 + kg) ^ (row & 7)) * 8);
      }
#pragma unroll
      for (int r = 0; r < 4; ++r)
#pragma unroll
        for (int c = 0; c < 4; ++c)
          acc[r][c] = __builtin_amdgcn_mfma_f32_16x16x32_f16(a[r], b[c],
                                                             acc[r][c], 0, 0, 0);
    }
    __syncthreads();
  }

  float g = G[0];
  if (!(__builtin_fabsf(g) >= 0.001f && __builtin_fabsf(g) <= 1000.0f)) g = 1.0f;
#pragma unroll
  for (int r = 0; r < 4; ++r)
#pragma unroll
    for (int c = 0; c < 4; ++c) {
      int col = bn + wc * 64 + c * 16 + fr;
      int row0 = bm + wr * 64 + r * 16 + kg * 4;
#pragma unroll
      for (int j = 0; j < 4; ++j)
        C[(size_t)(row0 + j) * N_DIM + col] = acc[r][c][j] * g;
    }
}

extern "C" void kernel_launch(void* const* d_in, const int* in_sizes, int n_in,
                              void* d_out, int out_size, void* d_ws,
                              size_t ws_size, hipStream_t stream) {
  const float* x = (const float*)d_in[0];
  const uint32_t* w32 = (const uint32_t*)d_in[1];
  const float* gamma = (const float*)d_in[2];
  float* out = (float*)d_out;
  (void)in_sizes; (void)n_in; (void)out_size;

  const size_t xf_bytes = (size_t)M_DIM * K_DIM * 2;  // 67.1 MB
  const size_t wf_bytes = (size_t)N_DIM * K_DIM * 2;  // 33.6 MB

  if (ws_size >= xf_bytes + wf_bytes) {
    _Float16* xf = (_Float16*)d_ws;
    _Float16* wf = (_Float16*)((char*)d_ws + xf_bytes);
    prep_x<<<M_DIM * K_DIM / 8 / 256, 256, 0, stream>>>((const float4*)x,
                                                        (ushort8*)xf);
    prep_w<<<N_DIM * K_DIM / 8 / 256, 256, 0, stream>>>((const uint2*)w32,
                                                        (uint4*)wf);
    gemm32<<<(M_DIM / 128) * (N_DIM / 256), 256, 0, stream>>>(xf, wf, gamma,
                                                              out);
  } else {
    dim3 grid(N_DIM / 128, M_DIM / 128);
    gemm_inline<<<grid, 256, 0, stream>>>(x, w32, gamma, out);
  }
}